// Round 13
// baseline (134.391 us; speedup 1.0000x reference)
//
#include <hip/hip_runtime.h>
#include <math.h>

#define TAU_F 0.07f
#define B_ 2
#define CIN 64
#define H_ 128
#define W_ 256
#define CC 96      // COST_CH
#define G_ 8
#define CG 12
#define DP 32
#define HW_ (H_*W_)
#define ROWF (W_*CG)   // floats per (b,h,g) row in plane layout = 3072

// ---------------------------------------------------------------------------
// Kernel 1: transpose weights [96][64] -> [64][96] (s_load path for proj).
// ---------------------------------------------------------------------------
__global__ void wtrans_kernel(const float* __restrict__ WL,
                              const float* __restrict__ WR,
                              float* __restrict__ WtL,
                              float* __restrict__ WtR) {
    int i = blockIdx.x * 256 + threadIdx.x;       // 0 .. 2*6144-1
    if (i >= 2 * CIN * CC) return;
    int side = i / (CIN * CC);
    int r = i % (CIN * CC);
    int c = r / CC;
    int o = r % CC;
    const float* src = side ? WR : WL;
    float* dst = side ? WtR : WtL;
    dst[r] = src[o * CIN + c];                    // Wt[c][o] = W[o][c]
}

// ---------------------------------------------------------------------------
// Kernel 2: projection + L2 norm (round-7 verified: readfirstlane scalarizes
// the weight base -> s_load path; dur ~27us at 1024 blocks). UNCHANGED.
// ---------------------------------------------------------------------------
__global__ __launch_bounds__(256, 4) void proj_kernel(
    const float* __restrict__ F_L, const float* __restrict__ F_R,
    const float* __restrict__ WtL, const float* __restrict__ WtR,
    float* __restrict__ outL, float* __restrict__ outR)
{
    __shared__ float ssS[256];

    const int blk  = blockIdx.x;
    const int side = blk & 1;
    const int wh   = (blk >> 1) & 1;
    const int h    = (blk >> 2) & 127;
    const int b    = blk >> 9;

    const int t    = threadIdx.x;
    const int half = t >> 7;             // wave-uniform
    const int wl   = t & 127;
    const int w    = wh * 128 + wl;

    const float* F  = side ? F_R : F_L;
    const float* Wt = side ? WtR : WtL;
    float* out      = side ? outR : outL;

    const int hoff = __builtin_amdgcn_readfirstlane(half * 48);
    const float* WtU = Wt + hoff;

    float y[48];
#pragma unroll
    for (int k = 0; k < 48; ++k) y[k] = 0.f;

    const float* fp = F + (size_t)b * CIN * HW_ + h * W_ + wh * 128 + wl;

#pragma unroll 4
    for (int c = 0; c < CIN; ++c) {
        float f = fp[c * HW_];
        const float* wr = WtU + c * CC;           // SGPR base -> s_load
#pragma unroll
        for (int k = 0; k < 48; ++k) y[k] = fmaf(f, wr[k], y[k]);
    }

    float ss = 0.f;
#pragma unroll
    for (int k = 0; k < 48; ++k) ss = fmaf(y[k], y[k], ss);
    ssS[t] = ss;
    __syncthreads();
    float tot = ss + ssS[t ^ 128];
    float r = 1.0f / fmaxf(sqrtf(tot), 1e-12f);

    size_t base = (size_t)(b * H_ + h) * (G_ * ROWF);
#pragma unroll
    for (int gq = 0; gq < 4; ++gq) {
        int g = half * 4 + gq;
#pragma unroll
        for (int j = 0; j < 3; ++j) {
            float4 v;
            v.x = y[gq*12 + j*4 + 0] * r;
            v.y = y[gq*12 + j*4 + 1] * r;
            v.z = y[gq*12 + j*4 + 2] * r;
            v.w = y[gq*12 + j*4 + 3] * r;
            *(float4*)&out[base + (size_t)g * ROWF + j * (W_*4) + w * 4] = v;
        }
    }
}

// ---------------------------------------------------------------------------
// Kernel 3: sim, sliding-window rewrite.
// One WAVE = one (b,g,h) row; block = 4 waves = 4 rows; 1024 blocks.
// Lane owns 4 pixels w=4l..4l+3. FL: 12 float4 in regs (from global,
// coalesced). FR: staged in LDS with XOR swizzle byte^=((byte>>7)&7)<<4
// (involution; makes both the 64B-stride reads and the stage writes
// bank-conflict-free). Per d-step: shift 4-wide FR register window by one
// pixel = 3 ds_read_b128 (vs 12 before), 48 FMA, one float4 store.
// Window slot of pixel p is p&3 (slots hold 4 consecutive pixels).
// ---------------------------------------------------------------------------
__global__ __launch_bounds__(256, 3) void sim_kernel(
    const float* __restrict__ PL, const float* __restrict__ PR,
    float* __restrict__ out)
{
    __shared__ float frS[4 * ROWF];   // 48 KB, one 12KB row per wave
    __shared__ float psiS[DP];

    const int tid = threadIdx.x;
    const int wv  = tid >> 6;
    const int l   = tid & 63;
    const int row = (blockIdx.x << 2) | wv;       // 0..4095
    const int h = row % H_;
    const int g = (row / H_) % G_;
    const int b = row / (H_ * G_);

    if (tid < DP)
        psiS[tid] = -sinf(6.28318530717958647692f * (float)tid / (float)DP) / TAU_F;

    const size_t base = ((size_t)(b * H_ + h) * G_ + g) * ROWF;
    const float* PRrow = PR + base;
    const float* PLrow = PL + base;
    char* frW = (char*)&frS[wv * ROWF];

    // stage FR row (swizzled): lane l writes pixels 4l..4l+3, planes 0..2
#pragma unroll
    for (int j = 0; j < 3; ++j) {
#pragma unroll
        for (int i = 0; i < 4; ++i) {
            int w = 4 * l + i;
            float4 v = *(const float4*)&PRrow[j * 1024 + w * 4];
            int byt = j * 4096 + w * 16;
            byt ^= ((byt >> 7) & 7) << 4;
            *(float4*)(frW + byt) = v;
        }
    }

    // FL for this lane's 4 pixels -> registers (coalesced 64B/lane/plane)
    float4 fl[4][3];
#pragma unroll
    for (int i = 0; i < 4; ++i)
#pragma unroll
        for (int j = 0; j < 3; ++j)
            fl[i][j] = *(const float4*)&PLrow[j * 1024 + (4 * l + i) * 4];

    __syncthreads();

    // init window: slot i holds pixel 4l+i (= pixel&3 convention)
    float4 wnd[4][3];
#pragma unroll
    for (int i = 0; i < 4; ++i) {
#pragma unroll
        for (int j = 0; j < 3; ++j) {
            int byt = j * 4096 + (4 * l + i) * 16;
            byt ^= ((byt >> 7) & 7) << 4;
            wnd[i][j] = *(const float4*)(frW + byt);
        }
    }

    const float A = -1.0f / (3.46410161513775459f * TAU_F);  // -1/(sqrt(12)*tau)
    const size_t ob = (((size_t)(b * G_ + g) * DP) * H_ + h) * (size_t)W_ + 4 * l;

#pragma unroll
    for (int d = 0; d < DP; ++d) {
        const float p = psiS[d];                  // uniform -> LDS broadcast
        float r[4];
#pragma unroll
        for (int i = 0; i < 4; ++i) {
            const int s = (i - d) & 3;            // compile-time after unroll
            float acc;
            acc = fl[i][0].x * wnd[s][0].x;
            acc = fmaf(fl[i][0].y, wnd[s][0].y, acc);
            acc = fmaf(fl[i][0].z, wnd[s][0].z, acc);
            acc = fmaf(fl[i][0].w, wnd[s][0].w, acc);
            acc = fmaf(fl[i][1].x, wnd[s][1].x, acc);
            acc = fmaf(fl[i][1].y, wnd[s][1].y, acc);
            acc = fmaf(fl[i][1].z, wnd[s][1].z, acc);
            acc = fmaf(fl[i][1].w, wnd[s][1].w, acc);
            acc = fmaf(fl[i][2].x, wnd[s][2].x, acc);
            acc = fmaf(fl[i][2].y, wnd[s][2].y, acc);
            acc = fmaf(fl[i][2].z, wnd[s][2].z, acc);
            acc = fmaf(fl[i][2].w, wnd[s][2].w, acc);
            r[i] = fmaf(acc, A, p);
        }
        *(float4*)&out[ob + (size_t)d * HW_] = make_float4(r[0], r[1], r[2], r[3]);

        if (d < DP - 1) {
            // slide: pixel 4l-(d+1) (clamped) enters slot (-(d+1))&3
            int wd = 4 * l - (d + 1); if (wd < 0) wd = 0;
            const int s = (-(d + 1)) & 3;
            const int byt0 = wd * 16;
#pragma unroll
            for (int j = 0; j < 3; ++j) {
                int byt = j * 4096 + byt0;
                byt ^= ((byt >> 7) & 7) << 4;
                wnd[s][j] = *(const float4*)(frW + byt);
            }
        }
    }
}

// ---------------------------------------------------------------------------
extern "C" void kernel_launch(void* const* d_in, const int* in_sizes, int n_in,
                              void* d_out, int out_size, void* d_ws, size_t ws_size,
                              hipStream_t stream) {
    const float* F_L = (const float*)d_in[0];
    const float* F_R = (const float*)d_in[1];
    const float* WL  = (const float*)d_in[2];
    const float* WR  = (const float*)d_in[3];
    float* out = (float*)d_out;
    float* ws  = (float*)d_ws;

    const size_t PROJ = (size_t)B_ * H_ * G_ * ROWF;   // 6,291,456 floats
    float* PLp = ws;
    float* PRp = ws + PROJ;
    float* WtL = ws + 2 * PROJ;
    float* WtR = WtL + CIN * CC;
    // ws bytes needed: (2*6291456 + 2*6144)*4 ≈ 48.05 MiB

    wtrans_kernel<<<(2 * CIN * CC + 255) / 256, 256, 0, stream>>>(WL, WR, WtL, WtR);
    proj_kernel<<<dim3(B_ * H_ * 2 * 2), 256, 0, stream>>>(F_L, F_R, WtL, WtR, PLp, PRp);
    sim_kernel<<<(B_ * G_ * H_) / 4, 256, 0, stream>>>(PLp, PRp, out);
}